// Round 4
// baseline (310.032 us; speedup 1.0000x reference)
//
#include <hip/hip_runtime.h>

#define NPATH  2048
#define DIM    64
#define NSTEPS 500

// TWO waves per path. Role 0 holds row `lane` of the drift matrix A and owns
// the state x; role 1 holds row `lane` of the diffusion matrix C and owns the
// dW stream. Per step both roles compute their 64-FMA mat-vec from the LDS
// broadcast row xs; role 1 writes the noise term to LDS; role 0 combines,
// updates x, stores ys, and republishes xs. 64 matrix floats/lane -> ~100
// VGPRs, no spill; 4096 waves = 4 waves/SIMD.
__attribute__((amdgpu_waves_per_eu(4, 4)))
__global__ __launch_bounds__(256) void sde_euler_kernel(
    const float* __restrict__ x0,
    const float* __restrict__ dW,
    const float* __restrict__ drift,
    const float* __restrict__ drift_bias,
    const float* __restrict__ diffusion,
    const float* __restrict__ diffusion_bias,
    const float* __restrict__ ts,
    float* __restrict__ out)
{
    __shared__ __align__(16) float xs[2][DIM];   // broadcast state row per path
    __shared__ float ns[2][DIM];                 // noise term, role1 -> role0
    __shared__ float2 dtp[NSTEPS + 1];           // {dt, sqrt(dt)} per step

    const int lane = threadIdx.x & 63;
    const int wave = threadIdx.x >> 6;
    const int p    = wave >> 1;                  // path slot within block
    const int role = wave & 1;                   // 0: drift/update, 1: diffusion/noise
    const int path = (blockIdx.x << 1) + p;

    // (dt, sqrt(dt)) table — dt = ts[i+1]-ts[i] in f32, matching the reference
    for (int i = threadIdx.x; i < NSTEPS; i += 256) {
        const float d = ts[i + 1] - ts[i];
        dtp[i] = make_float2(d, sqrtf(d));
    }
    if (threadIdx.x == 0) dtp[NSTEPS] = make_float2(0.f, 0.f);

    // This wave's matrix row (A for role 0, C for role 1) -> 64 VGPRs
    const float* __restrict__ M = role ? diffusion : drift;
    float Mrow[DIM];
#pragma unroll
    for (int k4 = 0; k4 < DIM / 4; ++k4) {
        const float4 m = *(const float4*)(M + lane * DIM + k4 * 4);
        Mrow[4 * k4 + 0] = m.x; Mrow[4 * k4 + 1] = m.y;
        Mrow[4 * k4 + 2] = m.z; Mrow[4 * k4 + 3] = m.w;
    }
#pragma unroll
    for (int k = 0; k < DIM; ++k) asm("" : "+v"(Mrow[k]));
    const float bias = role ? diffusion_bias[lane] : drift_bias[lane];

    float* outp = out + (size_t)path * (NSTEPS + 1) * DIM + lane;
    const float* dWp = dW + (size_t)path * NSTEPS * DIM + lane;

    float x = 0.f;
    float dw0 = 0.f, dw1 = 0.f, dw2 = 0.f, dw3 = 0.f;  // role1 prefetch ring
    if (role == 0) {
        x = x0[path * DIM + lane];
        outp[0] = x;                       // saved initial state
        xs[p][lane] = x;                   // broadcast row for step 0
    } else {
        dw0 = dWp[0];
        dw1 = dWp[DIM];
        dw2 = dWp[2 * DIM];
        dw3 = dWp[3 * DIM];
    }

    __syncthreads();                       // dtp + xs ready

    float2 dts = dtp[0];                   // {dt, sdt} for current step

    // consume DWCUR into dwc BEFORE the prefetch overwrites the slot
#define STEP(S, DWCUR, PF)                                                \
    {                                                                     \
        const float2 dtn = dtp[(S) + 1];                                  \
        float m0 = 0.f, m1 = 0.f, m2 = 0.f, m3 = 0.f;                     \
        _Pragma("unroll")                                                 \
        for (int k4 = 0; k4 < DIM / 4; ++k4) {                            \
            const float4 xv = *(const float4*)(&xs[p][k4 * 4]);           \
            m0 = fmaf(Mrow[4 * k4 + 0], xv.x, m0);                        \
            m1 = fmaf(Mrow[4 * k4 + 1], xv.y, m1);                        \
            m2 = fmaf(Mrow[4 * k4 + 2], xv.z, m2);                        \
            m3 = fmaf(Mrow[4 * k4 + 3], xv.w, m3);                        \
        }                                                                 \
        const float mv = ((m0 + m1) + (m2 + m3)) + bias;                  \
        if (role) {                                                       \
            const float dwc = (DWCUR);                                    \
            if (PF) DWCUR##_pf;                                           \
            ns[p][lane] = mv * (dts.y * dwc);                             \
        }                                                                 \
        __syncthreads();   /* ns ready; xs reads done */                  \
        if (!role) {                                                      \
            x = fmaf(dts.x, mv, x) + ns[p][lane];                         \
            __builtin_nontemporal_store(x, &outp[(size_t)((S) + 1) * DIM]); \
            xs[p][lane] = x;                                              \
        }                                                                 \
        dts = dtn;                                                        \
        __syncthreads();   /* xs for step S+1 published */                \
    }

#define dw0_pf dw0 = dWp[(size_t)(s + 4) * DIM]
#define dw1_pf dw1 = dWp[(size_t)(s + 5) * DIM]
#define dw2_pf dw2 = dWp[(size_t)(s + 6) * DIM]
#define dw3_pf dw3 = dWp[(size_t)(s + 7) * DIM]

    // main loop: steps 0..495, prefetching s+4..s+7 (<= 499, in range)
    for (int it = 0; it < (NSTEPS / 4) - 1; ++it) {
        const int s = it * 4;
        STEP(s + 0, dw0, 1)
        STEP(s + 1, dw1, 1)
        STEP(s + 2, dw2, 1)
        STEP(s + 3, dw3, 1)
    }
    // epilogue: steps 496..499, no prefetch
    {
        const int s = NSTEPS - 4;
        STEP(s + 0, dw0, 0)
        STEP(s + 1, dw1, 0)
        STEP(s + 2, dw2, 0)
        STEP(s + 3, dw3, 0)
    }
#undef STEP
#undef dw0_pf
#undef dw1_pf
#undef dw2_pf
#undef dw3_pf
}

extern "C" void kernel_launch(void* const* d_in, const int* in_sizes, int n_in,
                              void* d_out, int out_size, void* d_ws, size_t ws_size,
                              hipStream_t stream) {
    const float* x0             = (const float*)d_in[0];
    const float* dW             = (const float*)d_in[1];
    const float* drift          = (const float*)d_in[2];
    const float* drift_bias     = (const float*)d_in[3];
    const float* diffusion      = (const float*)d_in[4];
    const float* diffusion_bias = (const float*)d_in[5];
    const float* ts             = (const float*)d_in[6];
    float* out = (float*)d_out;

    dim3 grid(NPATH / 2);
    dim3 block(256);
    hipLaunchKernelGGL(sde_euler_kernel, grid, block, 0, stream,
                       x0, dW, drift, drift_bias, diffusion, diffusion_bias,
                       ts, out);
}